// Round 12
// baseline (1250.087 us; speedup 1.0000x reference)
//
#include <hip/hip_runtime.h>

#define THREADS 512
#define BT 16
#define TLEN 512
#define HD 128
#define NT 4      // 4 gate-tiles per wave: nt = gate (i,f,g,o), cols j = w*16..w*16+15
#define HSTR 136  // h row stride in shorts (272 B: MUST be mult. of 8 shorts for b128 alignment; r9 lesson)
#define XSTR 40   // x row stride in shorts (80 B: mult-of-8 AND 8 distinct bank-spans -> conflict-free)

// WhhL is stored in MFMA-FRAGMENT order (r10 lesson: 8B-misaligned ds_read_b128 is
// catastrophic; frag layout gives 16B-aligned, conflict-free, pad-free reads):
//   WhhL[(k>>3)*4096 + og*8 + (k&7)]  ->  read: WhhL + kk*16384 + q*4096 + col*8

// exp2-prescale constants folded into gate weights:
//   i,f,o cols scaled by -log2(e)  -> e = exp2(z') = exp(-z);  sigma = 1/(1+e)
//   g     cols scaled by +2log2(e) -> e = exp2(z') = exp(2z);  tanh = (e-1)/(e+1)
#define SC_IFO (-1.4426950408889634f)
#define SC_G   ( 2.8853900817779268f)

typedef __attribute__((ext_vector_type(8))) short bf16x8;
typedef __attribute__((ext_vector_type(4))) float f32x4;

__device__ __forceinline__ short f2bf(float f) {
  unsigned u = __float_as_uint(f);
  u += 0x7fff + ((u >> 16) & 1);
  return (short)(u >> 16);
}

// packed f32x2 -> bf16x2 (RNE, identical to f2bf on non-NaN)
__device__ __forceinline__ unsigned cvt_pk_bf16(float lo, float hi) {
  unsigned r;
  asm("v_cvt_pk_bf16_f32 %0, %1, %2" : "=v"(r) : "v"(lo), "v"(hi));
  return r;
}

__device__ __forceinline__ bf16x8 pack8(f32x4 a, f32x4 b) {
  bf16x8 r;
  r[0]=f2bf(a[0]); r[1]=f2bf(a[1]); r[2]=f2bf(a[2]); r[3]=f2bf(a[3]);
  r[4]=f2bf(b[0]); r[5]=f2bf(b[1]); r[6]=f2bf(b[2]); r[7]=f2bf(b[3]);
  return r;
}
__device__ __forceinline__ bf16x8 load8s(const float* p, float s) {
  const f32x4* q4 = (const f32x4*)p;
  return pack8(q4[0] * s, q4[1] * s);
}

// 8 waves, 1 block/CU, 2 waves/SIMD -> 256 unified regs/wave. Weights ~144 regs.
__global__ __launch_bounds__(THREADS, 2) void lstm_kernel(
    const float* __restrict__ xg,
    const float* __restrict__ Wih0, const float* __restrict__ Whh0,
    const float* __restrict__ bih0, const float* __restrict__ bhh0,
    const float* __restrict__ Wih1, const float* __restrict__ Whh1,
    const float* __restrict__ bih1, const float* __restrict__ bhh1,
    const float* __restrict__ gma, const float* __restrict__ bta,
    const float* __restrict__ mu,  const float* __restrict__ var,
    const float* __restrict__ W1,  const float* __restrict__ b1,
    const float* __restrict__ W2,  const float* __restrict__ b2,
    const float* __restrict__ Wf,  const float* __restrict__ bfv,
    const int* __restrict__ psP,
    float* __restrict__ dout)
{
  // ---- LDS (~159.2 KB of 163,840) ----
  __shared__ __align__(16) short WhhL[512*HD];     // Whh0, frag-order (see header), prescaled
  __shared__ __align__(16) short h0A[2][BT*HSTR];  // bf16 A-layout [row][j]
  __shared__ __align__(16) short h1A[2][BT*HSTR];
  __shared__ __align__(16) short xA[2][BT*XSTR];   // [b][k0..31], col8 = 1.0 (bias)
  __shared__ float a1L[64*BT];
  __shared__ float W2L[4*65];
  __shared__ float WcL[8*68];   // fused Wf@W2 (8x64), 68-padded
  __shared__ float bcL[8];      // fused Wf@b2 + bf
  __shared__ float b2L[4];
  __shared__ float b1cL[64];
  __shared__ float sLs[HD];

  const int tid = threadIdx.x;
  const int w   = tid >> 6;      // wave 0..7, owns j cols [16w, 16w+16) for all 4 gates
  const int l   = tid & 63;
  const int ln  = l & 15;
  const int q   = l >> 4;
  const int gb0 = blockIdx.x * BT;
  const int ps  = psP[0];

  // ---- init LDS phase A ----
  for (int i = tid; i < BT*XSTR; i += THREADS) { xA[0][i] = 0; xA[1][i] = 0; }
  for (int i = tid; i < BT*HSTR; i += THREADS) {
    h0A[0][i] = 0; h0A[1][i] = 0; h1A[0][i] = 0; h1A[1][i] = 0;
  }
  if (tid < BT) {
    xA[0][tid*XSTR + 8] = (short)0x3F80;   // 1.0 bf16 -> layer0 bias slot
    xA[1][tid*XSTR + 8] = (short)0x3F80;
  }
  if (tid < HD) sLs[tid] = gma[tid] * rsqrtf(var[tid] + 1e-5f);
  if (tid < 260) { int o = tid / 65, p = tid % 65; W2L[tid] = (p < 64) ? W2[o*64 + p] : 0.f; }
  // fused FC: Wc[i][p] = sum_o Wf[i][o]*W2[o][p];  bc[i] = sum_o Wf[i][o]*b2[o] + bf[i]
  {
    int i0 = tid >> 6, p = tid & 63;   // all 512 threads: i0 = 0..7
    float acc = 0.f;
    #pragma unroll
    for (int o = 0; o < 4; o++) acc += Wf[i0*4 + o] * W2[o*64 + p];
    WcL[i0*68 + p] = acc;
  }
  if (tid < 8) {
    float acc = bfv[tid];
    #pragma unroll
    for (int o = 0; o < 4; o++) acc += Wf[tid*4 + o] * b2[o];
    bcL[tid] = acc;
  }
  if (tid < 4)  b2L[tid] = b2[tid];
  for (int i = tid; i < 512*HD; i += THREADS) {   // Whh0 -> LDS frag-order, prescaled
    int og = i >> 7, k = i & 127;
    float sc = ((og >> 7) == 2) ? SC_G : SC_IFO;
    WhhL[((k >> 3) << 12) + (og << 3) + (k & 7)] = f2bf(Whh0[i] * sc);
  }

  // ---- register-resident weights (bf16), per-gate tiles, exp2-prescaled ----
  bf16x8 wih0f[NT], wih1f[NT][4], whh1f[NT][4];
  float b1sum[NT];
  #pragma unroll
  for (int nt = 0; nt < NT; nt++) {
    int og = nt*HD + (w << 4) + ln;    // gate nt, col j = w*16+ln
    const float sc = (nt == 2) ? SC_G : SC_IFO;
    // Wih0 frag (K padded to 32; k==8 carries layer0 bias, matching xA col8=1)
    {
      bf16x8 r;
      #pragma unroll
      for (int j = 0; j < 8; j++) {
        int k = q*8 + j;
        float v = 0.f;
        if (k < 8) v = Wih0[og*8 + k];
        else if (k == 8) v = bih0[og] + bhh0[og];
        r[j] = f2bf(v * sc);
      }
      wih0f[nt] = r;
    }
    #pragma unroll
    for (int kk = 0; kk < 4; kk++) {
      int k0 = kk*32 + q*8;
      wih1f[nt][kk] = load8s(Wih1 + og*HD + k0, sc);
      whh1f[nt][kk] = load8s(Whh1 + og*HD + k0, sc);
    }
    b1sum[nt] = (bih1[og] + bhh1[og]) * sc;
  }
  __syncthreads();  // phase A visible (sLs for below)

  // ---- phase B: needs sLs ----
  if (tid < 64) {
    float acc = b1[tid];
    for (int j = 0; j < HD; j++)
      acc += (bta[j] - mu[j]*sLs[j]) * W1[tid*HD + j];
    b1cL[tid] = acc;
  }
  // stage x(0) into xA[0]
  if (tid < 128) {
    const int b = tid >> 3, i2 = tid & 7;
    xA[0][b*XSTR + i2] = f2bf(xg[(size_t)(gb0 + b)*(TLEN*8) + i2]);
  }
  __syncthreads();  // b1cL + x(0) ready; all init done

  f32x4 c0s = {0.f,0.f,0.f,0.f};   // holds 2*log2(e)*c  (scaled cell state)
  f32x4 c1s = {0.f,0.f,0.f,0.f};

  const int aoffX = ln*XSTR + q*8;            // x A-frag offset (shorts)
  const int aoffH = ln*HSTR + q*8;            // h A-frag offset, + kk*32
  const int hwoff = (q*4)*HSTR + (w<<4) + ln; // h write base: rows q*4+r, col j
  const int cbL   = (q << 12) + ((w << 4) + ln) * 8;  // WhhL frag base; + nt*1024 + kk*16384

  // ---- activation tail: prescaled z -> exp2 direct; merged reciprocals:
  //   i*g = (eg-1)/((1+ei)(1+eg)),  o*tanh(c) = (ec-1)/((1+eo)(1+ec))
  //   5 exp2 + 3 rcp per element ----
  auto gates = [&](const f32x4& gi, const f32x4& gf, const f32x4& gg, const f32x4& go,
                   f32x4& cs, short* hw) {
    float hv[4];
    #pragma unroll
    for (int r = 0; r < 4; r++) {
      float ei = __builtin_amdgcn_exp2f(gi[r]);     // = exp(-z_i)
      float ef = __builtin_amdgcn_exp2f(gf[r]);     // = exp(-z_f)
      float eg = __builtin_amdgcn_exp2f(gg[r]);     // = exp(+2 z_g)
      float eo = __builtin_amdgcn_exp2f(go[r]);     // = exp(-z_o)
      float f   = __builtin_amdgcn_rcpf(1.0f + ef);
      float rig = __builtin_amdgcn_rcpf((1.0f + ei) * (1.0f + eg));
      float igs = (SC_G * eg - SC_G) * rig;         // = 2log2e * i * g
      float c   = f * cs[r] + igs;                  // scaled cell state
      cs[r] = c;
      float ec  = __builtin_amdgcn_exp2f(c);        // = exp(2 c_true)
      float roc = __builtin_amdgcn_rcpf((1.0f + eo) * (1.0f + ec));
      hv[r] = (ec - 1.0f) * roc;                    // = o * tanh(c_true)
    }
    unsigned p01 = cvt_pk_bf16(hv[0], hv[1]);
    unsigned p23 = cvt_pk_bf16(hv[2], hv[3]);
    hw[0*HSTR] = (short)p01;
    hw[1*HSTR] = (short)(p01 >> 16);
    hw[2*HSTR] = (short)p23;
    hw[3*HSTR] = (short)(p23 >> 16);
  };

  // ---- L0 MFMA issue with distance-1 WhhL prefetch: tile nt+1's B-frags are
  //      ~5 MFMAs deep in flight when consumed (hides ds_read latency) ----
  auto issueL0 = [&](const short* xr, const bf16x8* ah, f32x4* acc) {
    bf16x8 ax = *(const bf16x8*)(xr + aoffX);
    bf16x8 wbP[4];
    #pragma unroll
    for (int kk = 0; kk < 4; kk++)
      wbP[kk] = *(const bf16x8*)(WhhL + cbL + 0*1024 + kk*16384);
    #pragma unroll
    for (int nt = 0; nt < NT; nt++) {
      bf16x8 wbN[4];
      if (nt < NT-1) {
        #pragma unroll
        for (int kk = 0; kk < 4; kk++)
          wbN[kk] = *(const bf16x8*)(WhhL + cbL + (nt+1)*1024 + kk*16384);
      }
      f32x4 a = {0.f,0.f,0.f,0.f};
      a = __builtin_amdgcn_mfma_f32_16x16x32_bf16(ax, wih0f[nt], a, 0, 0, 0);
      #pragma unroll
      for (int kk = 0; kk < 4; kk++)
        a = __builtin_amdgcn_mfma_f32_16x16x32_bf16(ah[kk], wbP[kk], a, 0, 0, 0);
      acc[nt] = a;
      if (nt < NT-1) {
        #pragma unroll
        for (int kk = 0; kk < 4; kk++) wbP[kk] = wbN[kk];
      }
    }
  };
  auto issueL1 = [&](const bf16x8* ah, const bf16x8* a1v, f32x4* acc) {
    #pragma unroll
    for (int nt = 0; nt < NT; nt++) {
      f32x4 a; a[0]=a[1]=a[2]=a[3]=b1sum[nt];
      #pragma unroll
      for (int kk = 0; kk < 4; kk++) {
        a = __builtin_amdgcn_mfma_f32_16x16x32_bf16(ah[kk],  wih1f[nt][kk], a, 0, 0, 0);
        a = __builtin_amdgcn_mfma_f32_16x16x32_bf16(a1v[kk], whh1f[nt][kk], a, 0, 0, 0);
      }
      acc[nt] = a;
    }
  };

  // -------- serial layer forms (decoder) --------
  auto layer0 = [&](const short* xr, const bf16x8* ah, short* h0w) {
    f32x4 ac[NT];
    issueL0(xr, ah, ac);
    gates(ac[0], ac[1], ac[2], ac[3], c0s, h0w + hwoff);
  };
  auto layer1 = [&](const bf16x8* ah, const short* h1r, short* h1w) {
    bf16x8 a1k[4];
    #pragma unroll
    for (int kk = 0; kk < 4; kk++)
      a1k[kk] = *(const bf16x8*)(h1r + aoffH + kk*32);
    f32x4 ac[NT];
    issueL1(ah, a1k, ac);
    gates(ac[0], ac[1], ac[2], ac[3], c1s, h1w + hwoff);
  };

  // ================= encoder: pipelined, ONE barrier per iteration ==========
  // iter k: layer0(k) [x(k), h0(k-1) -> h0(k)]  ||  layer1(k-1) [h0(k-1), h1(k-2) -> h1(k-1)]
  // ISSUE ORDER within the wave: all ds_reads -> ALL 52 MFMAs -> all gates VALU.
  auto enc_iter = [&](int k, const short* xr, short* xw,
                      const short* h0r, short* h0w,
                      const short* h1r, short* h1w, bool doL0, bool doL1) {
    const int b = tid >> 3, i2 = tid & 7;
    const bool pf = doL0 && (k + 1 < TLEN) && (tid < 128);
    float xp = 0.f;
    if (pf) xp = xg[(size_t)(gb0 + b)*(TLEN*8) + (size_t)(k+1)*8 + i2]; // in flight under compute
    bf16x8 ah[4];                       // h0(k-1) frags, shared by both layers
    #pragma unroll
    for (int kk = 0; kk < 4; kk++)
      ah[kk] = *(const bf16x8*)(h0r + aoffH + kk*32);
    bf16x8 a1k[4];
    if (doL1) {
      #pragma unroll
      for (int kk = 0; kk < 4; kk++)
        a1k[kk] = *(const bf16x8*)(h1r + aoffH + kk*32);
    }
    f32x4 ac0[NT], ac1[NT];
    if (doL0) issueL0(xr, ah, ac0);      // L0 MFMA block (20), prefetched B-frags
    if (doL1) issueL1(ah, a1k, ac1);     // L1 MFMA block (32) — before any gates
    if (doL0) gates(ac0[0], ac0[1], ac0[2], ac0[3], c0s, h0w + hwoff);
    if (doL1) gates(ac1[0], ac1[1], ac1[2], ac1[3], c1s, h1w + hwoff);
    if (pf) xw[b*XSTR + i2] = f2bf(xp);  // other x buffer: no race with xr readers
    __syncthreads();                     // h0(k), h1(k-1), x(k+1) visible
  };

  enc_iter(0, xA[0], xA[1], h0A[1], h0A[0], h1A[0], h1A[1], true, false);
  enc_iter(1, xA[1], xA[0], h0A[0], h0A[1], h1A[1], h1A[0], true, true);
  for (int k = 2; k < TLEN; k += 2) {
    enc_iter(k,     xA[0], xA[1], h0A[1], h0A[0], h1A[0], h1A[1], true, true);
    enc_iter(k + 1, xA[1], xA[0], h0A[0], h0A[1], h1A[1], h1A[0], true, true);
  }
  enc_iter(TLEN, xA[0], xA[1], h0A[1], h0A[0], h1A[0], h1A[1], false, true);
  // state: h0(511) in h0A[1], h1(511) in h1A[1], x(511) in xA[1].

  // ---- decoder-only weights materialized AFTER the encoder (fewer live regs
  //      in the hot loop); sLs persists in LDS. FC path is NOT prescaled. ----
  bf16x8 w1f[4];
  #pragma unroll
  for (int kk = 0; kk < 4; kk++) {
    bf16x8 r;
    if (w < 4) {
      int p = w*16 + ln;
      #pragma unroll
      for (int j = 0; j < 8; j++) {
        int k = kk*32 + q*8 + j;
        r[j] = f2bf(sLs[k] * W1[p*HD + k]);
      }
    } else {
      #pragma unroll
      for (int j = 0; j < 8; j++) r[j] = 0;
    }
    w1f[kk] = r;
  }

  // ================= decoder (serial; rb flipped since state sits in [1]) ====
  for (int s = 0; s < ps; s++) {
    int rb = (s & 1) ^ 1;
    __syncthreads();  // xA[1] + buffer turnover ready
    {
      bf16x8 ah[4];
      #pragma unroll
      for (int kk = 0; kk < 4; kk++)
        ah[kk] = *(const bf16x8*)(h0A[rb] + aoffH + kk*32);
      layer0(xA[1], ah, h0A[rb^1]);
    }
    __syncthreads();
    {
      bf16x8 ah[4];
      #pragma unroll
      for (int kk = 0; kk < 4; kk++)
        ah[kk] = *(const bf16x8*)(h0A[rb^1] + aoffH + kk*32);
      layer1(ah, h1A[rb], h1A[rb^1]);
    }
    const short* h1n = h1A[rb^1];
    __syncthreads();  // h1 new visible to all waves
    // ---- a1 = relu(h1 @ (bn-folded W1)^T + b1c): MFMA on waves 0..3
    if (w < 4) {
      f32x4 aa = {0.f,0.f,0.f,0.f};
      #pragma unroll
      for (int kk = 0; kk < 4; kk++) {
        bf16x8 ahn = *(const bf16x8*)(h1n + aoffH + kk*32);
        aa = __builtin_amdgcn_mfma_f32_16x16x32_bf16(ahn, w1f[kk], aa, 0, 0, 0);
      }
      float bb = b1cL[w*16 + ln];
      #pragma unroll
      for (int r = 0; r < 4; r++)
        a1L[(w*16 + ln)*16 + q*4 + r] = fmaxf(aa[r] + bb, 0.f);
    }
    __syncthreads();
    // ---- concurrent: xin = a1 @ Wc^T + bc (tid<128) ; dout = a1 @ W2^T + b2 (tid 128..191)
    if (tid < 128) {
      int b = tid >> 3, i2 = tid & 7;
      float v = bcL[i2];
      for (int p = 0; p < 64; p++)
        v += a1L[p*16 + b] * WcL[i2*68 + p];
      xA[1][b*XSTR + i2] = f2bf(v);
    } else if (tid < 192) {
      int t = tid - 128, b = t & 15, o = t >> 4;
      float acc2 = b2L[o];
      for (int p = 0; p < 64; p++)
        acc2 += a1L[p*16 + b] * W2L[o*65 + p];
      dout[(size_t)(gb0 + b)*(ps*4) + s*4 + o] = acc2;
    }
  }
}

extern "C" void kernel_launch(void* const* d_in, const int* in_sizes, int n_in,
                              void* d_out, int out_size, void* d_ws, size_t ws_size,
                              hipStream_t stream) {
  (void)in_sizes; (void)n_in; (void)d_ws; (void)ws_size; (void)out_size;
  lstm_kernel<<<dim3(4096/BT), dim3(THREADS), 0, stream>>>(
      (const float*)d_in[0],  (const float*)d_in[1],  (const float*)d_in[2],
      (const float*)d_in[3],  (const float*)d_in[4],  (const float*)d_in[5],
      (const float*)d_in[6],  (const float*)d_in[7],  (const float*)d_in[8],
      (const float*)d_in[9],  (const float*)d_in[10], (const float*)d_in[11],
      (const float*)d_in[12], (const float*)d_in[13], (const float*)d_in[14],
      (const float*)d_in[15], (const float*)d_in[16], (const float*)d_in[17],
      (const float*)d_in[18], (const int*)d_in[19],   (float*)d_out);
}

// Round 13
// 1244.153 us; speedup vs baseline: 1.0048x; 1.0048x over previous
//
#include <hip/hip_runtime.h>

#define THREADS 512
#define BT 16
#define TLEN 512
#define HD 128
#define NT 4      // 4 gate-tiles per wave: nt = gate (i,f,g,o), cols j = w*16..w*16+15
#define HSTR 136  // h row stride in shorts (272 B: MUST be mult. of 8 shorts for b128 alignment; r9 lesson)

// WhhL is stored in MFMA-FRAGMENT order (r10 lesson: 8B-misaligned ds_read_b128 is
// catastrophic; frag layout gives 16B-aligned, conflict-free, pad-free reads):
//   WhhL[(k>>3)*4096 + og*8 + (k&7)]  ->  read: WhhL + kk*16384 + q*4096 + col*8

// exp2-prescale constants folded into gate weights:
//   i,f,o cols scaled by -log2(e)  -> e = exp2(z') = exp(-z);  sigma = 1/(1+e)
//   g     cols scaled by +2log2(e) -> e = exp2(z') = exp(2z);  tanh = (e-1)/(e+1)
#define SC_IFO (-1.4426950408889634f)
#define SC_G   ( 2.8853900817779268f)

typedef __attribute__((ext_vector_type(8))) short bf16x8;
typedef __attribute__((ext_vector_type(4))) float f32x4;

__device__ __forceinline__ short f2bf(float f) {
  unsigned u = __float_as_uint(f);
  u += 0x7fff + ((u >> 16) & 1);
  return (short)(u >> 16);
}

// packed f32x2 -> bf16x2 (RNE, identical to f2bf on non-NaN)
__device__ __forceinline__ unsigned cvt_pk_bf16(float lo, float hi) {
  unsigned r;
  asm("v_cvt_pk_bf16_f32 %0, %1, %2" : "=v"(r) : "v"(lo), "v"(hi));
  return r;
}

__device__ __forceinline__ bf16x8 pack8(f32x4 a, f32x4 b) {
  bf16x8 r;
  r[0]=f2bf(a[0]); r[1]=f2bf(a[1]); r[2]=f2bf(a[2]); r[3]=f2bf(a[3]);
  r[4]=f2bf(b[0]); r[5]=f2bf(b[1]); r[6]=f2bf(b[2]); r[7]=f2bf(b[3]);
  return r;
}
__device__ __forceinline__ bf16x8 load8s(const float* p, float s) {
  const f32x4* q4 = (const f32x4*)p;
  return pack8(q4[0] * s, q4[1] * s);
}

// 8 waves, 1 block/CU, 2 waves/SIMD -> 256 unified regs/wave. Weights ~144 regs.
__global__ __launch_bounds__(THREADS, 2) void lstm_kernel(
    const float* __restrict__ xg,
    const float* __restrict__ Wih0, const float* __restrict__ Whh0,
    const float* __restrict__ bih0, const float* __restrict__ bhh0,
    const float* __restrict__ Wih1, const float* __restrict__ Whh1,
    const float* __restrict__ bih1, const float* __restrict__ bhh1,
    const float* __restrict__ gma, const float* __restrict__ bta,
    const float* __restrict__ mu,  const float* __restrict__ var,
    const float* __restrict__ W1,  const float* __restrict__ b1,
    const float* __restrict__ W2,  const float* __restrict__ b2,
    const float* __restrict__ Wf,  const float* __restrict__ bfv,
    const int* __restrict__ psP,
    float* __restrict__ dout)
{
  // ---- LDS (~158.7 KB of 163,840) ----
  __shared__ __align__(16) short WhhL[512*HD];     // Whh0, frag-order (see header), prescaled
  __shared__ __align__(16) short h0A[2][BT*HSTR];  // bf16 A-layout [row][j]
  __shared__ __align__(16) short h1A[2][BT*HSTR];
  __shared__ __align__(16) short xA[2][BT*32];     // [b][k0..31], col8 = 1.0 (bias)
  __shared__ float a1L[64*BT];
  __shared__ float W2L[4*65];
  __shared__ float WcL[8*68];   // fused Wf@W2 (8x64), 68-padded
  __shared__ float bcL[8];      // fused Wf@b2 + bf
  __shared__ float b2L[4];
  __shared__ float b1cL[64];
  __shared__ float sLs[HD];

  const int tid = threadIdx.x;
  const int w   = tid >> 6;      // wave 0..7, owns j cols [16w, 16w+16) for all 4 gates
  const int l   = tid & 63;
  const int ln  = l & 15;
  const int q   = l >> 4;
  const int gb0 = blockIdx.x * BT;
  const int ps  = psP[0];

  // ---- init LDS phase A ----
  for (int i = tid; i < BT*32; i += THREADS) { xA[0][i] = 0; xA[1][i] = 0; }
  for (int i = tid; i < BT*HSTR; i += THREADS) {
    h0A[0][i] = 0; h0A[1][i] = 0; h1A[0][i] = 0; h1A[1][i] = 0;
  }
  if (tid < BT) {
    xA[0][tid*32 + 8] = (short)0x3F80;   // 1.0 bf16 -> layer0 bias slot
    xA[1][tid*32 + 8] = (short)0x3F80;
  }
  if (tid < HD) sLs[tid] = gma[tid] * rsqrtf(var[tid] + 1e-5f);
  if (tid < 260) { int o = tid / 65, p = tid % 65; W2L[tid] = (p < 64) ? W2[o*64 + p] : 0.f; }
  // fused FC: Wc[i][p] = sum_o Wf[i][o]*W2[o][p];  bc[i] = sum_o Wf[i][o]*b2[o] + bf[i]
  {
    int i0 = tid >> 6, p = tid & 63;   // all 512 threads: i0 = 0..7
    float acc = 0.f;
    #pragma unroll
    for (int o = 0; o < 4; o++) acc += Wf[i0*4 + o] * W2[o*64 + p];
    WcL[i0*68 + p] = acc;
  }
  if (tid < 8) {
    float acc = bfv[tid];
    #pragma unroll
    for (int o = 0; o < 4; o++) acc += Wf[tid*4 + o] * b2[o];
    bcL[tid] = acc;
  }
  if (tid < 4)  b2L[tid] = b2[tid];
  for (int i = tid; i < 512*HD; i += THREADS) {   // Whh0 -> LDS frag-order, prescaled
    int og = i >> 7, k = i & 127;
    float sc = ((og >> 7) == 2) ? SC_G : SC_IFO;
    WhhL[((k >> 3) << 12) + (og << 3) + (k & 7)] = f2bf(Whh0[i] * sc);
  }

  // ---- register-resident weights (bf16), per-gate tiles, exp2-prescaled ----
  bf16x8 wih0f[NT], wih1f[NT][4], whh1f[NT][4];
  float b1sum[NT];
  #pragma unroll
  for (int nt = 0; nt < NT; nt++) {
    int og = nt*HD + (w << 4) + ln;    // gate nt, col j = w*16+ln
    const float sc = (nt == 2) ? SC_G : SC_IFO;
    // Wih0 frag (K padded to 32; k==8 carries layer0 bias, matching xA col8=1)
    {
      bf16x8 r;
      #pragma unroll
      for (int j = 0; j < 8; j++) {
        int k = q*8 + j;
        float v = 0.f;
        if (k < 8) v = Wih0[og*8 + k];
        else if (k == 8) v = bih0[og] + bhh0[og];
        r[j] = f2bf(v * sc);
      }
      wih0f[nt] = r;
    }
    #pragma unroll
    for (int kk = 0; kk < 4; kk++) {
      int k0 = kk*32 + q*8;
      wih1f[nt][kk] = load8s(Wih1 + og*HD + k0, sc);
      whh1f[nt][kk] = load8s(Whh1 + og*HD + k0, sc);
    }
    b1sum[nt] = (bih1[og] + bhh1[og]) * sc;
  }
  __syncthreads();  // phase A visible (sLs for below)

  // ---- phase B: needs sLs ----
  if (tid < 64) {
    float acc = b1[tid];
    for (int j = 0; j < HD; j++)
      acc += (bta[j] - mu[j]*sLs[j]) * W1[tid*HD + j];
    b1cL[tid] = acc;
  }
  // stage x(0) into xA[0]
  if (tid < 128) {
    const int b = tid >> 3, i2 = tid & 7;
    xA[0][b*32 + i2] = f2bf(xg[(size_t)(gb0 + b)*(TLEN*8) + i2]);
  }
  __syncthreads();  // b1cL + x(0) ready; all init done

  f32x4 c0s = {0.f,0.f,0.f,0.f};   // holds 2*log2(e)*c  (scaled cell state)
  f32x4 c1s = {0.f,0.f,0.f,0.f};

  const int aoffX = ln*32   + q*8;            // x A-frag offset (shorts)
  const int aoffH = ln*HSTR + q*8;            // h A-frag offset, + kk*32
  const int hwoff = (q*4)*HSTR + (w<<4) + ln; // h write base: rows q*4+r, col j
  const int cbL   = (q << 12) + ((w << 4) + ln) * 8;  // WhhL frag base; + nt*1024 + kk*16384

  // ---- activation tail: prescaled z -> exp2 direct; merged reciprocals:
  //   i*g = (eg-1)/((1+ei)(1+eg)),  o*tanh(c) = (ec-1)/((1+eo)(1+ec))
  //   5 exp2 + 3 rcp per element ----
  auto gates = [&](const f32x4& gi, const f32x4& gf, const f32x4& gg, const f32x4& go,
                   f32x4& cs, short* hw) {
    float hv[4];
    #pragma unroll
    for (int r = 0; r < 4; r++) {
      float ei = __builtin_amdgcn_exp2f(gi[r]);     // = exp(-z_i)
      float ef = __builtin_amdgcn_exp2f(gf[r]);     // = exp(-z_f)
      float eg = __builtin_amdgcn_exp2f(gg[r]);     // = exp(+2 z_g)
      float eo = __builtin_amdgcn_exp2f(go[r]);     // = exp(-z_o)
      float f   = __builtin_amdgcn_rcpf(1.0f + ef);
      float rig = __builtin_amdgcn_rcpf((1.0f + ei) * (1.0f + eg));
      float igs = (SC_G * eg - SC_G) * rig;         // = 2log2e * i * g
      float c   = f * cs[r] + igs;                  // scaled cell state
      cs[r] = c;
      float ec  = __builtin_amdgcn_exp2f(c);        // = exp(2 c_true)
      float roc = __builtin_amdgcn_rcpf((1.0f + eo) * (1.0f + ec));
      hv[r] = (ec - 1.0f) * roc;                    // = o * tanh(c_true)
    }
    unsigned p01 = cvt_pk_bf16(hv[0], hv[1]);
    unsigned p23 = cvt_pk_bf16(hv[2], hv[3]);
    hw[0*HSTR] = (short)p01;
    hw[1*HSTR] = (short)(p01 >> 16);
    hw[2*HSTR] = (short)p23;
    hw[3*HSTR] = (short)(p23 >> 16);
  };

  // -------- layer 0 (serial form, used by decoder) --------
  auto layer0 = [&](const short* xr, const bf16x8* ah, short* h0w) {
    bf16x8 ax = *(const bf16x8*)(xr + aoffX);
    f32x4 ac[NT];
    #pragma unroll
    for (int nt = 0; nt < NT; nt++) {
      f32x4 a = {0.f,0.f,0.f,0.f};
      a = __builtin_amdgcn_mfma_f32_16x16x32_bf16(ax, wih0f[nt], a, 0, 0, 0);
      #pragma unroll
      for (int kk = 0; kk < 4; kk++) {
        bf16x8 wb = *(const bf16x8*)(WhhL + cbL + nt*1024 + kk*16384);
        a = __builtin_amdgcn_mfma_f32_16x16x32_bf16(ah[kk], wb, a, 0, 0, 0);
      }
      ac[nt] = a;
    }
    gates(ac[0], ac[1], ac[2], ac[3], c0s, h0w + hwoff);
  };

  // -------- layer 1 (serial form, used by decoder) --------
  auto layer1 = [&](const bf16x8* ah, const short* h1r, short* h1w) {
    bf16x8 a1k[4];
    #pragma unroll
    for (int kk = 0; kk < 4; kk++)
      a1k[kk] = *(const bf16x8*)(h1r + aoffH + kk*32);
    f32x4 ac[NT];
    #pragma unroll
    for (int nt = 0; nt < NT; nt++) {
      f32x4 a; a[0]=a[1]=a[2]=a[3]=b1sum[nt];
      #pragma unroll
      for (int kk = 0; kk < 4; kk++) {
        a = __builtin_amdgcn_mfma_f32_16x16x32_bf16(ah[kk],  wih1f[nt][kk], a, 0, 0, 0);
        a = __builtin_amdgcn_mfma_f32_16x16x32_bf16(a1k[kk], whh1f[nt][kk], a, 0, 0, 0);
      }
      ac[nt] = a;
    }
    gates(ac[0], ac[1], ac[2], ac[3], c1s, h1w + hwoff);
  };

  // ================= encoder: pipelined, ONE barrier per iteration ==========
  // iter k: layer0(k) [x(k), h0(k-1) -> h0(k)]  ||  layer1(k-1) [h0(k-1), h1(k-2) -> h1(k-1)]
  // ISSUE ORDER within the wave: all ds_reads -> ALL 52 MFMAs -> all gates VALU.
  // In-order issue + async pipes => gates VALU issues while MFMAs still execute.
  auto enc_iter = [&](int k, const short* xr, short* xw,
                      const short* h0r, short* h0w,
                      const short* h1r, short* h1w, bool doL0, bool doL1) {
    const int b = tid >> 3, i2 = tid & 7;
    const bool pf = doL0 && (k + 1 < TLEN) && (tid < 128);
    float xp = 0.f;
    if (pf) xp = xg[(size_t)(gb0 + b)*(TLEN*8) + (size_t)(k+1)*8 + i2]; // in flight under compute
    bf16x8 ah[4];                       // h0(k-1) frags, shared by both layers
    #pragma unroll
    for (int kk = 0; kk < 4; kk++)
      ah[kk] = *(const bf16x8*)(h0r + aoffH + kk*32);
    bf16x8 a1k[4];
    if (doL1) {
      #pragma unroll
      for (int kk = 0; kk < 4; kk++)
        a1k[kk] = *(const bf16x8*)(h1r + aoffH + kk*32);
    }
    f32x4 ac0[NT], ac1[NT];
    if (doL0) {                          // L0 MFMA block (20)
      bf16x8 ax = *(const bf16x8*)(xr + aoffX);
      #pragma unroll
      for (int nt = 0; nt < NT; nt++) {
        f32x4 a = {0.f,0.f,0.f,0.f};
        a = __builtin_amdgcn_mfma_f32_16x16x32_bf16(ax, wih0f[nt], a, 0, 0, 0);
        #pragma unroll
        for (int kk = 0; kk < 4; kk++) {
          bf16x8 wb = *(const bf16x8*)(WhhL + cbL + nt*1024 + kk*16384);
          a = __builtin_amdgcn_mfma_f32_16x16x32_bf16(ah[kk], wb, a, 0, 0, 0);
        }
        ac0[nt] = a;
      }
    }
    if (doL1) {                          // L1 MFMA block (32) — issued before any gates
      #pragma unroll
      for (int nt = 0; nt < NT; nt++) {
        f32x4 a; a[0]=a[1]=a[2]=a[3]=b1sum[nt];
        #pragma unroll
        for (int kk = 0; kk < 4; kk++) {
          a = __builtin_amdgcn_mfma_f32_16x16x32_bf16(ah[kk],  wih1f[nt][kk], a, 0, 0, 0);
          a = __builtin_amdgcn_mfma_f32_16x16x32_bf16(a1k[kk], whh1f[nt][kk], a, 0, 0, 0);
        }
        ac1[nt] = a;
      }
    }
    if (doL0) gates(ac0[0], ac0[1], ac0[2], ac0[3], c0s, h0w + hwoff);
    if (doL1) gates(ac1[0], ac1[1], ac1[2], ac1[3], c1s, h1w + hwoff);
    if (pf) xw[b*32 + i2] = f2bf(xp);   // other x buffer: no race with xr readers
    __syncthreads();                    // h0(k), h1(k-1), x(k+1) visible
  };

  enc_iter(0, xA[0], xA[1], h0A[1], h0A[0], h1A[0], h1A[1], true, false);
  enc_iter(1, xA[1], xA[0], h0A[0], h0A[1], h1A[1], h1A[0], true, true);
  for (int k = 2; k < TLEN; k += 2) {
    enc_iter(k,     xA[0], xA[1], h0A[1], h0A[0], h1A[0], h1A[1], true, true);
    enc_iter(k + 1, xA[1], xA[0], h0A[0], h0A[1], h1A[1], h1A[0], true, true);
  }
  enc_iter(TLEN, xA[0], xA[1], h0A[1], h0A[0], h1A[0], h1A[1], false, true);
  // state: h0(511) in h0A[1], h1(511) in h1A[1], x(511) in xA[1].

  // ---- decoder-only weights materialized AFTER the encoder (fewer live regs
  //      in the hot loop); sLs persists in LDS. FC path is NOT prescaled. ----
  bf16x8 w1f[4];
  #pragma unroll
  for (int kk = 0; kk < 4; kk++) {
    bf16x8 r;
    if (w < 4) {
      int p = w*16 + ln;
      #pragma unroll
      for (int j = 0; j < 8; j++) {
        int k = kk*32 + q*8 + j;
        r[j] = f2bf(sLs[k] * W1[p*HD + k]);
      }
    } else {
      #pragma unroll
      for (int j = 0; j < 8; j++) r[j] = 0;
    }
    w1f[kk] = r;
  }

  // ================= decoder (serial; rb flipped since state sits in [1]) ====
  for (int s = 0; s < ps; s++) {
    int rb = (s & 1) ^ 1;
    __syncthreads();  // xA[1] + buffer turnover ready
    {
      bf16x8 ah[4];
      #pragma unroll
      for (int kk = 0; kk < 4; kk++)
        ah[kk] = *(const bf16x8*)(h0A[rb] + aoffH + kk*32);
      layer0(xA[1], ah, h0A[rb^1]);
    }
    __syncthreads();
    {
      bf16x8 ah[4];
      #pragma unroll
      for (int kk = 0; kk < 4; kk++)
        ah[kk] = *(const bf16x8*)(h0A[rb^1] + aoffH + kk*32);
      layer1(ah, h1A[rb], h1A[rb^1]);
    }
    const short* h1n = h1A[rb^1];
    __syncthreads();  // h1 new visible to all waves
    // ---- a1 = relu(h1 @ (bn-folded W1)^T + b1c): MFMA on waves 0..3
    if (w < 4) {
      f32x4 aa = {0.f,0.f,0.f,0.f};
      #pragma unroll
      for (int kk = 0; kk < 4; kk++) {
        bf16x8 ahn = *(const bf16x8*)(h1n + aoffH + kk*32);
        aa = __builtin_amdgcn_mfma_f32_16x16x32_bf16(ahn, w1f[kk], aa, 0, 0, 0);
      }
      float bb = b1cL[w*16 + ln];
      #pragma unroll
      for (int r = 0; r < 4; r++)
        a1L[(w*16 + ln)*16 + q*4 + r] = fmaxf(aa[r] + bb, 0.f);
    }
    __syncthreads();
    // ---- concurrent: xin = a1 @ Wc^T + bc (tid<128) ; dout = a1 @ W2^T + b2 (tid 128..191)
    if (tid < 128) {
      int b = tid >> 3, i2 = tid & 7;
      float v = bcL[i2];
      for (int p = 0; p < 64; p++)
        v += a1L[p*16 + b] * WcL[i2*68 + p];
      xA[1][b*32 + i2] = f2bf(v);
    } else if (tid < 192) {
      int t = tid - 128, b = t & 15, o = t >> 4;
      float acc2 = b2L[o];
      for (int p = 0; p < 64; p++)
        acc2 += a1L[p*16 + b] * W2L[o*65 + p];
      dout[(size_t)(gb0 + b)*(ps*4) + s*4 + o] = acc2;
    }
  }
}

extern "C" void kernel_launch(void* const* d_in, const int* in_sizes, int n_in,
                              void* d_out, int out_size, void* d_ws, size_t ws_size,
                              hipStream_t stream) {
  (void)in_sizes; (void)n_in; (void)d_ws; (void)ws_size; (void)out_size;
  lstm_kernel<<<dim3(4096/BT), dim3(THREADS), 0, stream>>>(
      (const float*)d_in[0],  (const float*)d_in[1],  (const float*)d_in[2],
      (const float*)d_in[3],  (const float*)d_in[4],  (const float*)d_in[5],
      (const float*)d_in[6],  (const float*)d_in[7],  (const float*)d_in[8],
      (const float*)d_in[9],  (const float*)d_in[10], (const float*)d_in[11],
      (const float*)d_in[12], (const float*)d_in[13], (const float*)d_in[14],
      (const float*)d_in[15], (const float*)d_in[16], (const float*)d_in[17],
      (const float*)d_in[18], (const int*)d_in[19],   (float*)d_out);
}

// Round 14
// 1196.023 us; speedup vs baseline: 1.0452x; 1.0402x over previous
//
#include <hip/hip_runtime.h>

#define THREADS 512
#define BT 16
#define TLEN 512
#define HD 128
#define NT 4      // 4 gate-tiles per wave: nt = gate (i,f,g,o), cols j = w*16..w*16+15
#define HSTR 136  // h row stride in shorts (272 B: MUST be mult. of 8 shorts for b128 alignment; r9 lesson)

// WhhL is stored in MFMA-FRAGMENT order (r10 lesson: 8B-misaligned ds_read_b128 is
// catastrophic; frag layout gives 16B-aligned, conflict-free, pad-free reads):
//   WhhL[(k>>3)*4096 + og*8 + (k&7)]  ->  read: WhhL + kk*16384 + q*4096 + col*8

// exp2-prescale constants folded into gate weights:
//   i,f,o cols scaled by -log2(e)  -> e = exp2(z') = exp(-z);  sigma = 1/(1+e)
//   g     cols scaled by +2log2(e) -> e = exp2(z') = exp(2z);  tanh = (e-1)/(e+1)
#define SC_IFO (-1.4426950408889634f)
#define SC_G   ( 2.8853900817779268f)

typedef __attribute__((ext_vector_type(8))) short bf16x8;
typedef __attribute__((ext_vector_type(4))) float f32x4;

__device__ __forceinline__ short f2bf(float f) {
  unsigned u = __float_as_uint(f);
  u += 0x7fff + ((u >> 16) & 1);
  return (short)(u >> 16);
}

// packed f32x2 -> bf16x2 (RNE, identical to f2bf on non-NaN)
__device__ __forceinline__ unsigned cvt_pk_bf16(float lo, float hi) {
  unsigned r;
  asm("v_cvt_pk_bf16_f32 %0, %1, %2" : "=v"(r) : "v"(lo), "v"(hi));
  return r;
}

__device__ __forceinline__ bf16x8 pack8(f32x4 a, f32x4 b) {
  bf16x8 r;
  r[0]=f2bf(a[0]); r[1]=f2bf(a[1]); r[2]=f2bf(a[2]); r[3]=f2bf(a[3]);
  r[4]=f2bf(b[0]); r[5]=f2bf(b[1]); r[6]=f2bf(b[2]); r[7]=f2bf(b[3]);
  return r;
}
__device__ __forceinline__ bf16x8 load8s(const float* p, float s) {
  const f32x4* q4 = (const f32x4*)p;
  return pack8(q4[0] * s, q4[1] * s);
}

// 8 waves, 1 block/CU, 2 waves/SIMD -> 256 unified regs/wave. Weights ~144 regs.
__global__ __launch_bounds__(THREADS, 2) void lstm_kernel(
    const float* __restrict__ xg,
    const float* __restrict__ Wih0, const float* __restrict__ Whh0,
    const float* __restrict__ bih0, const float* __restrict__ bhh0,
    const float* __restrict__ Wih1, const float* __restrict__ Whh1,
    const float* __restrict__ bih1, const float* __restrict__ bhh1,
    const float* __restrict__ gma, const float* __restrict__ bta,
    const float* __restrict__ mu,  const float* __restrict__ var,
    const float* __restrict__ W1,  const float* __restrict__ b1,
    const float* __restrict__ W2,  const float* __restrict__ b2,
    const float* __restrict__ Wf,  const float* __restrict__ bfv,
    const int* __restrict__ psP,
    float* __restrict__ dout)
{
  // ---- LDS (~158.7 KB of 163,840) ----
  __shared__ __align__(16) short WhhL[512*HD];     // Whh0, frag-order (see header), prescaled
  __shared__ __align__(16) short h0A[2][BT*HSTR];  // bf16 A-layout [row][j]
  __shared__ __align__(16) short h1A[2][BT*HSTR];
  __shared__ __align__(16) short xA[2][BT*32];     // [b][k0..31], col8 = 1.0 (bias)
  __shared__ float a1L[64*BT];
  __shared__ float W2L[4*65];
  __shared__ float WcL[8*68];   // fused Wf@W2 (8x64), 68-padded
  __shared__ float bcL[8];      // fused Wf@b2 + bf
  __shared__ float b2L[4];
  __shared__ float b1cL[64];
  __shared__ float sLs[HD];

  const int tid = threadIdx.x;
  const int w   = tid >> 6;      // wave 0..7, owns j cols [16w, 16w+16) for all 4 gates
  const int l   = tid & 63;
  const int ln  = l & 15;
  const int q   = l >> 4;
  const int gb0 = blockIdx.x * BT;
  const int ps  = psP[0];

  // ---- init LDS phase A ----
  for (int i = tid; i < BT*32; i += THREADS) { xA[0][i] = 0; xA[1][i] = 0; }
  for (int i = tid; i < BT*HSTR; i += THREADS) {
    h0A[0][i] = 0; h0A[1][i] = 0; h1A[0][i] = 0; h1A[1][i] = 0;
  }
  if (tid < BT) {
    xA[0][tid*32 + 8] = (short)0x3F80;   // 1.0 bf16 -> layer0 bias slot
    xA[1][tid*32 + 8] = (short)0x3F80;
  }
  if (tid < HD) sLs[tid] = gma[tid] * rsqrtf(var[tid] + 1e-5f);
  if (tid < 260) { int o = tid / 65, p = tid % 65; W2L[tid] = (p < 64) ? W2[o*64 + p] : 0.f; }
  // fused FC: Wc[i][p] = sum_o Wf[i][o]*W2[o][p];  bc[i] = sum_o Wf[i][o]*b2[o] + bf[i]
  {
    int i0 = tid >> 6, p = tid & 63;   // all 512 threads: i0 = 0..7
    float acc = 0.f;
    #pragma unroll
    for (int o = 0; o < 4; o++) acc += Wf[i0*4 + o] * W2[o*64 + p];
    WcL[i0*68 + p] = acc;
  }
  if (tid < 8) {
    float acc = bfv[tid];
    #pragma unroll
    for (int o = 0; o < 4; o++) acc += Wf[tid*4 + o] * b2[o];
    bcL[tid] = acc;
  }
  if (tid < 4)  b2L[tid] = b2[tid];
  for (int i = tid; i < 512*HD; i += THREADS) {   // Whh0 -> LDS frag-order, prescaled
    int og = i >> 7, k = i & 127;
    float sc = ((og >> 7) == 2) ? SC_G : SC_IFO;
    WhhL[((k >> 3) << 12) + (og << 3) + (k & 7)] = f2bf(Whh0[i] * sc);
  }

  // ---- register-resident weights (bf16), per-gate tiles, exp2-prescaled ----
  bf16x8 wih0f[NT], wih1f[NT][4], whh1f[NT][4];
  float b1sum[NT];
  #pragma unroll
  for (int nt = 0; nt < NT; nt++) {
    int og = nt*HD + (w << 4) + ln;    // gate nt, col j = w*16+ln
    const float sc = (nt == 2) ? SC_G : SC_IFO;
    // Wih0 frag (K padded to 32; k==8 carries layer0 bias, matching xA col8=1)
    {
      bf16x8 r;
      #pragma unroll
      for (int j = 0; j < 8; j++) {
        int k = q*8 + j;
        float v = 0.f;
        if (k < 8) v = Wih0[og*8 + k];
        else if (k == 8) v = bih0[og] + bhh0[og];
        r[j] = f2bf(v * sc);
      }
      wih0f[nt] = r;
    }
    #pragma unroll
    for (int kk = 0; kk < 4; kk++) {
      int k0 = kk*32 + q*8;
      wih1f[nt][kk] = load8s(Wih1 + og*HD + k0, sc);
      whh1f[nt][kk] = load8s(Whh1 + og*HD + k0, sc);
    }
    b1sum[nt] = (bih1[og] + bhh1[og]) * sc;
  }
  __syncthreads();  // phase A visible (sLs for below)

  // ---- phase B: needs sLs ----
  if (tid < 64) {
    float acc = b1[tid];
    for (int j = 0; j < HD; j++)
      acc += (bta[j] - mu[j]*sLs[j]) * W1[tid*HD + j];
    b1cL[tid] = acc;
  }
  // stage x(0) into xA[0]
  if (tid < 128) {
    const int b = tid >> 3, i2 = tid & 7;
    xA[0][b*32 + i2] = f2bf(xg[(size_t)(gb0 + b)*(TLEN*8) + i2]);
  }
  __syncthreads();  // b1cL + x(0) ready; all init done

  f32x4 c0s = {0.f,0.f,0.f,0.f};   // holds 2*log2(e)*c  (scaled cell state)
  f32x4 c1s = {0.f,0.f,0.f,0.f};

  const int aoffX = ln*32   + q*8;            // x A-frag offset (shorts)
  const int aoffH = ln*HSTR + q*8;            // h A-frag offset, + kk*32
  const int hwoff = (q*4)*HSTR + (w<<4) + ln; // h write base: rows q*4+r, col j
  const int cbL   = (q << 12) + ((w << 4) + ln) * 8;  // WhhL frag base; + nt*1024 + kk*16384

  // ---- activation tail: prescaled z -> exp2 direct; FULLY merged reciprocals:
  //   c  = [cs*(1+ei)(1+eg) + (SC_G*eg-SC_G)*(1+ef)] / ((1+ef)(1+ei)(1+eg))
  //   h  = (ec-1) / ((1+eo)(1+ec))
  //   5 exp2 + 2 rcp per element (was 5+3) ----
  auto gates = [&](const f32x4& gi, const f32x4& gf, const f32x4& gg, const f32x4& go,
                   f32x4& cs, short* hw) {
    float hv[4];
    #pragma unroll
    for (int r = 0; r < 4; r++) {
      float ei = __builtin_amdgcn_exp2f(gi[r]);     // = exp(-z_i)
      float ef = __builtin_amdgcn_exp2f(gf[r]);     // = exp(-z_f)
      float eg = __builtin_amdgcn_exp2f(gg[r]);     // = exp(+2 z_g)
      float eo = __builtin_amdgcn_exp2f(go[r]);     // = exp(-z_o)
      float pi  = 1.0f + ei, pf = 1.0f + ef, pg = 1.0f + eg;
      float pig = pi * pg;
      float num = cs[r] * pig + (SC_G * eg - SC_G) * pf;
      float c   = num * __builtin_amdgcn_rcpf(pf * pig);   // scaled cell state
      cs[r] = c;
      float ec  = __builtin_amdgcn_exp2f(c);        // = exp(2 c_true)
      float roc = __builtin_amdgcn_rcpf((1.0f + eo) * (1.0f + ec));
      hv[r] = (ec - 1.0f) * roc;                    // = o * tanh(c_true)
    }
    unsigned p01 = cvt_pk_bf16(hv[0], hv[1]);
    unsigned p23 = cvt_pk_bf16(hv[2], hv[3]);
    hw[0*HSTR] = (short)p01;
    hw[1*HSTR] = (short)(p01 >> 16);
    hw[2*HSTR] = (short)p23;
    hw[3*HSTR] = (short)(p23 >> 16);
  };

  // -------- layer 0 (serial form, used by decoder) --------
  auto layer0 = [&](const short* xr, const bf16x8* ah, short* h0w) {
    bf16x8 ax = *(const bf16x8*)(xr + aoffX);
    f32x4 ac[NT];
    #pragma unroll
    for (int nt = 0; nt < NT; nt++) {
      f32x4 a = {0.f,0.f,0.f,0.f};
      a = __builtin_amdgcn_mfma_f32_16x16x32_bf16(ax, wih0f[nt], a, 0, 0, 0);
      #pragma unroll
      for (int kk = 0; kk < 4; kk++) {
        bf16x8 wb = *(const bf16x8*)(WhhL + cbL + nt*1024 + kk*16384);
        a = __builtin_amdgcn_mfma_f32_16x16x32_bf16(ah[kk], wb, a, 0, 0, 0);
      }
      ac[nt] = a;
    }
    gates(ac[0], ac[1], ac[2], ac[3], c0s, h0w + hwoff);
  };

  // -------- layer 1 (serial form, used by decoder) --------
  auto layer1 = [&](const bf16x8* ah, const short* h1r, short* h1w) {
    bf16x8 a1k[4];
    #pragma unroll
    for (int kk = 0; kk < 4; kk++)
      a1k[kk] = *(const bf16x8*)(h1r + aoffH + kk*32);
    f32x4 ac[NT];
    #pragma unroll
    for (int nt = 0; nt < NT; nt++) {
      f32x4 a; a[0]=a[1]=a[2]=a[3]=b1sum[nt];
      #pragma unroll
      for (int kk = 0; kk < 4; kk++) {
        a = __builtin_amdgcn_mfma_f32_16x16x32_bf16(ah[kk],  wih1f[nt][kk], a, 0, 0, 0);
        a = __builtin_amdgcn_mfma_f32_16x16x32_bf16(a1k[kk], whh1f[nt][kk], a, 0, 0, 0);
      }
      ac[nt] = a;
    }
    gates(ac[0], ac[1], ac[2], ac[3], c1s, h1w + hwoff);
  };

  // ================= encoder: pipelined, ONE barrier per iteration ==========
  // iter k: layer0(k) [x(k), h0(k-1) -> h0(k)]  ||  layer1(k-1) [h0(k-1), h1(k-2) -> h1(k-1)]
  // ISSUE ORDER within the wave: all ds_reads -> ALL 52 MFMAs -> all gates VALU.
  // In-order issue + async pipes => gates VALU issues while MFMAs still execute.
  auto enc_iter = [&](int k, const short* xr, short* xw,
                      const short* h0r, short* h0w,
                      const short* h1r, short* h1w, bool doL0, bool doL1) {
    const int b = tid >> 3, i2 = tid & 7;
    const bool pf = doL0 && (k + 1 < TLEN) && (tid < 128);
    float xp = 0.f;
    if (pf) xp = xg[(size_t)(gb0 + b)*(TLEN*8) + (size_t)(k+1)*8 + i2]; // in flight under compute
    bf16x8 ah[4];                       // h0(k-1) frags, shared by both layers
    #pragma unroll
    for (int kk = 0; kk < 4; kk++)
      ah[kk] = *(const bf16x8*)(h0r + aoffH + kk*32);
    bf16x8 a1k[4];
    if (doL1) {
      #pragma unroll
      for (int kk = 0; kk < 4; kk++)
        a1k[kk] = *(const bf16x8*)(h1r + aoffH + kk*32);
    }
    f32x4 ac0[NT], ac1[NT];
    if (doL0) {                          // L0 MFMA block (20)
      bf16x8 ax = *(const bf16x8*)(xr + aoffX);
      #pragma unroll
      for (int nt = 0; nt < NT; nt++) {
        f32x4 a = {0.f,0.f,0.f,0.f};
        a = __builtin_amdgcn_mfma_f32_16x16x32_bf16(ax, wih0f[nt], a, 0, 0, 0);
        #pragma unroll
        for (int kk = 0; kk < 4; kk++) {
          bf16x8 wb = *(const bf16x8*)(WhhL + cbL + nt*1024 + kk*16384);
          a = __builtin_amdgcn_mfma_f32_16x16x32_bf16(ah[kk], wb, a, 0, 0, 0);
        }
        ac0[nt] = a;
      }
    }
    if (doL1) {                          // L1 MFMA block (32) — issued before any gates
      #pragma unroll
      for (int nt = 0; nt < NT; nt++) {
        f32x4 a; a[0]=a[1]=a[2]=a[3]=b1sum[nt];
        #pragma unroll
        for (int kk = 0; kk < 4; kk++) {
          a = __builtin_amdgcn_mfma_f32_16x16x32_bf16(ah[kk],  wih1f[nt][kk], a, 0, 0, 0);
          a = __builtin_amdgcn_mfma_f32_16x16x32_bf16(a1k[kk], whh1f[nt][kk], a, 0, 0, 0);
        }
        ac1[nt] = a;
      }
    }
    if (doL0) gates(ac0[0], ac0[1], ac0[2], ac0[3], c0s, h0w + hwoff);
    if (doL1) gates(ac1[0], ac1[1], ac1[2], ac1[3], c1s, h1w + hwoff);
    if (pf) xw[b*32 + i2] = f2bf(xp);   // other x buffer: no race with xr readers
    __syncthreads();                    // h0(k), h1(k-1), x(k+1) visible
  };

  enc_iter(0, xA[0], xA[1], h0A[1], h0A[0], h1A[0], h1A[1], true, false);
  enc_iter(1, xA[1], xA[0], h0A[0], h0A[1], h1A[1], h1A[0], true, true);
  for (int k = 2; k < TLEN; k += 2) {
    enc_iter(k,     xA[0], xA[1], h0A[1], h0A[0], h1A[0], h1A[1], true, true);
    enc_iter(k + 1, xA[1], xA[0], h0A[0], h0A[1], h1A[1], h1A[0], true, true);
  }
  enc_iter(TLEN, xA[0], xA[1], h0A[1], h0A[0], h1A[0], h1A[1], false, true);
  // state: h0(511) in h0A[1], h1(511) in h1A[1], x(511) in xA[1].

  // ---- decoder-only weights materialized AFTER the encoder (fewer live regs
  //      in the hot loop); sLs persists in LDS. FC path is NOT prescaled. ----
  bf16x8 w1f[4];
  #pragma unroll
  for (int kk = 0; kk < 4; kk++) {
    bf16x8 r;
    if (w < 4) {
      int p = w*16 + ln;
      #pragma unroll
      for (int j = 0; j < 8; j++) {
        int k = kk*32 + q*8 + j;
        r[j] = f2bf(sLs[k] * W1[p*HD + k]);
      }
    } else {
      #pragma unroll
      for (int j = 0; j < 8; j++) r[j] = 0;
    }
    w1f[kk] = r;
  }

  // ================= decoder (serial; rb flipped since state sits in [1]) ====
  for (int s = 0; s < ps; s++) {
    int rb = (s & 1) ^ 1;
    __syncthreads();  // xA[1] + buffer turnover ready
    {
      bf16x8 ah[4];
      #pragma unroll
      for (int kk = 0; kk < 4; kk++)
        ah[kk] = *(const bf16x8*)(h0A[rb] + aoffH + kk*32);
      layer0(xA[1], ah, h0A[rb^1]);
    }
    __syncthreads();
    {
      bf16x8 ah[4];
      #pragma unroll
      for (int kk = 0; kk < 4; kk++)
        ah[kk] = *(const bf16x8*)(h0A[rb^1] + aoffH + kk*32);
      layer1(ah, h1A[rb], h1A[rb^1]);
    }
    const short* h1n = h1A[rb^1];
    __syncthreads();  // h1 new visible to all waves
    // ---- a1 = relu(h1 @ (bn-folded W1)^T + b1c): MFMA on waves 0..3
    if (w < 4) {
      f32x4 aa = {0.f,0.f,0.f,0.f};
      #pragma unroll
      for (int kk = 0; kk < 4; kk++) {
        bf16x8 ahn = *(const bf16x8*)(h1n + aoffH + kk*32);
        aa = __builtin_amdgcn_mfma_f32_16x16x32_bf16(ahn, w1f[kk], aa, 0, 0, 0);
      }
      float bb = b1cL[w*16 + ln];
      #pragma unroll
      for (int r = 0; r < 4; r++)
        a1L[(w*16 + ln)*16 + q*4 + r] = fmaxf(aa[r] + bb, 0.f);
    }
    __syncthreads();
    // ---- concurrent: xin = a1 @ Wc^T + bc (tid<128) ; dout = a1 @ W2^T + b2 (tid 128..191)
    if (tid < 128) {
      int b = tid >> 3, i2 = tid & 7;
      float v = bcL[i2];
      for (int p = 0; p < 64; p++)
        v += a1L[p*16 + b] * WcL[i2*68 + p];
      xA[1][b*32 + i2] = f2bf(v);
    } else if (tid < 192) {
      int t = tid - 128, b = t & 15, o = t >> 4;
      float acc2 = b2L[o];
      for (int p = 0; p < 64; p++)
        acc2 += a1L[p*16 + b] * W2L[o*65 + p];
      dout[(size_t)(gb0 + b)*(ps*4) + s*4 + o] = acc2;
    }
  }
}

extern "C" void kernel_launch(void* const* d_in, const int* in_sizes, int n_in,
                              void* d_out, int out_size, void* d_ws, size_t ws_size,
                              hipStream_t stream) {
  (void)in_sizes; (void)n_in; (void)d_ws; (void)ws_size; (void)out_size;
  lstm_kernel<<<dim3(4096/BT), dim3(THREADS), 0, stream>>>(
      (const float*)d_in[0],  (const float*)d_in[1],  (const float*)d_in[2],
      (const float*)d_in[3],  (const float*)d_in[4],  (const float*)d_in[5],
      (const float*)d_in[6],  (const float*)d_in[7],  (const float*)d_in[8],
      (const float*)d_in[9],  (const float*)d_in[10], (const float*)d_in[11],
      (const float*)d_in[12], (const float*)d_in[13], (const float*)d_in[14],
      (const float*)d_in[15], (const float*)d_in[16], (const float*)d_in[17],
      (const float*)d_in[18], (const int*)d_in[19],   (float*)d_out);
}

// Round 15
// 1188.540 us; speedup vs baseline: 1.0518x; 1.0063x over previous
//
#include <hip/hip_runtime.h>

#define THREADS 512
#define BT 16
#define TLEN 512
#define HD 128
#define NT 4      // 4 gate-tiles per wave: nt = gate (i,f,g,o), cols j = w*16..w*16+15
#define HSTR 136  // h row stride in shorts (272 B: MUST be mult. of 8 shorts for b128 alignment; r9 lesson)

// WhhL is stored in MFMA-FRAGMENT order (r10 lesson: 8B-misaligned ds_read_b128 is
// catastrophic; frag layout gives 16B-aligned, conflict-free, pad-free reads):
//   WhhL[(k>>3)*4096 + og*8 + (k&7)]  ->  read: WhhL + kk*16384 + q*4096 + col*8

// exp2-prescale constants folded into gate weights:
//   i,f,o cols scaled by -log2(e)  -> e = exp2(z') = exp(-z);  sigma = 1/(1+e)
//   g     cols scaled by +2log2(e) -> e = exp2(z') = exp(2z);  tanh = (e-1)/(e+1)
#define SC_IFO (-1.4426950408889634f)
#define SC_G   ( 2.8853900817779268f)

typedef __attribute__((ext_vector_type(8))) short bf16x8;
typedef __attribute__((ext_vector_type(4))) float f32x4;

__device__ __forceinline__ short f2bf(float f) {
  unsigned u = __float_as_uint(f);
  u += 0x7fff + ((u >> 16) & 1);
  return (short)(u >> 16);
}

// packed f32x2 -> bf16x2 (RNE, identical to f2bf on non-NaN)
__device__ __forceinline__ unsigned cvt_pk_bf16(float lo, float hi) {
  unsigned r;
  asm("v_cvt_pk_bf16_f32 %0, %1, %2" : "=v"(r) : "v"(lo), "v"(hi));
  return r;
}

__device__ __forceinline__ bf16x8 pack8(f32x4 a, f32x4 b) {
  bf16x8 r;
  r[0]=f2bf(a[0]); r[1]=f2bf(a[1]); r[2]=f2bf(a[2]); r[3]=f2bf(a[3]);
  r[4]=f2bf(b[0]); r[5]=f2bf(b[1]); r[6]=f2bf(b[2]); r[7]=f2bf(b[3]);
  return r;
}
__device__ __forceinline__ bf16x8 load8s(const float* p, float s) {
  const f32x4* q4 = (const f32x4*)p;
  return pack8(q4[0] * s, q4[1] * s);
}

// 8 waves, 1 block/CU, 2 waves/SIMD -> 256 unified regs/wave. Weights ~144 regs.
__global__ __launch_bounds__(THREADS, 2) void lstm_kernel(
    const float* __restrict__ xg,
    const float* __restrict__ Wih0, const float* __restrict__ Whh0,
    const float* __restrict__ bih0, const float* __restrict__ bhh0,
    const float* __restrict__ Wih1, const float* __restrict__ Whh1,
    const float* __restrict__ bih1, const float* __restrict__ bhh1,
    const float* __restrict__ gma, const float* __restrict__ bta,
    const float* __restrict__ mu,  const float* __restrict__ var,
    const float* __restrict__ W1,  const float* __restrict__ b1,
    const float* __restrict__ W2,  const float* __restrict__ b2,
    const float* __restrict__ Wf,  const float* __restrict__ bfv,
    const int* __restrict__ psP,
    float* __restrict__ dout)
{
  // ---- LDS (~159.0 KB of 163,840) ----
  __shared__ __align__(16) short WhhL[512*HD];     // Whh0, frag-order (see header), prescaled
  __shared__ __align__(16) short h0A[2][BT*HSTR];  // bf16 A-layout [row][j]
  __shared__ __align__(16) short h1A[2][BT*HSTR];
  __shared__ __align__(16) short xA[2][BT*32];     // [b][k0..31], col8 = 1.0 (bias)
  __shared__ __align__(16) float a1L[16*68];       // a1, b-major stride 68 (272B: 16B-aligned rows)
  __shared__ __align__(16) float W2L[4*68];        // W2, stride 68
  __shared__ __align__(16) float WcL[8*68];        // fused Wf@W2 (8x64), stride 68
  __shared__ float bcL[8];      // fused Wf@b2 + bf
  __shared__ float b2L[4];
  __shared__ float b1cL[64];
  __shared__ float sLs[HD];

  const int tid = threadIdx.x;
  const int w   = tid >> 6;      // wave 0..7, owns j cols [16w, 16w+16) for all 4 gates
  const int l   = tid & 63;
  const int ln  = l & 15;
  const int q   = l >> 4;
  const int gb0 = blockIdx.x * BT;
  const int ps  = psP[0];

  // ---- init LDS phase A ----
  for (int i = tid; i < BT*32; i += THREADS) { xA[0][i] = 0; xA[1][i] = 0; }
  for (int i = tid; i < BT*HSTR; i += THREADS) {
    h0A[0][i] = 0; h0A[1][i] = 0; h1A[0][i] = 0; h1A[1][i] = 0;
  }
  if (tid < BT) {
    xA[0][tid*32 + 8] = (short)0x3F80;   // 1.0 bf16 -> layer0 bias slot
    xA[1][tid*32 + 8] = (short)0x3F80;
  }
  if (tid < HD) sLs[tid] = gma[tid] * rsqrtf(var[tid] + 1e-5f);
  if (tid < 272) { int o = tid / 68, p = tid % 68; W2L[tid] = (p < 64) ? W2[o*64 + p] : 0.f; }
  // fused FC: Wc[i][p] = sum_o Wf[i][o]*W2[o][p];  bc[i] = sum_o Wf[i][o]*b2[o] + bf[i]
  {
    int i0 = tid >> 6, p = tid & 63;   // all 512 threads: i0 = 0..7
    float acc = 0.f;
    #pragma unroll
    for (int o = 0; o < 4; o++) acc += Wf[i0*4 + o] * W2[o*64 + p];
    WcL[i0*68 + p] = acc;
    if (p >= 60) WcL[i0*68 + p + 4] = 0.f;   // pad cols 64..67
  }
  if (tid < 8) {
    float acc = bfv[tid];
    #pragma unroll
    for (int o = 0; o < 4; o++) acc += Wf[tid*4 + o] * b2[o];
    bcL[tid] = acc;
  }
  if (tid < 4)  b2L[tid] = b2[tid];
  if (tid >= 448) {   // pad a1L cols 64..67 once (rows b = tid-448 >> 2 ... simple: zero all pad)
    // covered below by full a1L zero init
  }
  for (int i = tid; i < 16*68; i += THREADS) a1L[i] = 0.f;   // zero incl. pad cols
  for (int i = tid; i < 512*HD; i += THREADS) {   // Whh0 -> LDS frag-order, prescaled
    int og = i >> 7, k = i & 127;
    float sc = ((og >> 7) == 2) ? SC_G : SC_IFO;
    WhhL[((k >> 3) << 12) + (og << 3) + (k & 7)] = f2bf(Whh0[i] * sc);
  }

  // ---- register-resident weights (bf16), per-gate tiles, exp2-prescaled ----
  bf16x8 wih0f[NT], wih1f[NT][4], whh1f[NT][4];
  float b1sum[NT];
  #pragma unroll
  for (int nt = 0; nt < NT; nt++) {
    int og = nt*HD + (w << 4) + ln;    // gate nt, col j = w*16+ln
    const float sc = (nt == 2) ? SC_G : SC_IFO;
    // Wih0 frag (K padded to 32; k==8 carries layer0 bias, matching xA col8=1)
    {
      bf16x8 r;
      #pragma unroll
      for (int j = 0; j < 8; j++) {
        int k = q*8 + j;
        float v = 0.f;
        if (k < 8) v = Wih0[og*8 + k];
        else if (k == 8) v = bih0[og] + bhh0[og];
        r[j] = f2bf(v * sc);
      }
      wih0f[nt] = r;
    }
    #pragma unroll
    for (int kk = 0; kk < 4; kk++) {
      int k0 = kk*32 + q*8;
      wih1f[nt][kk] = load8s(Wih1 + og*HD + k0, sc);
      whh1f[nt][kk] = load8s(Whh1 + og*HD + k0, sc);
    }
    b1sum[nt] = (bih1[og] + bhh1[og]) * sc;
  }
  __syncthreads();  // phase A visible (sLs for below)

  // ---- phase B: needs sLs ----
  if (tid < 64) {
    float acc = b1[tid];
    for (int j = 0; j < HD; j++)
      acc += (bta[j] - mu[j]*sLs[j]) * W1[tid*HD + j];
    b1cL[tid] = acc;
  }
  // stage x(0) into xA[0]
  if (tid < 128) {
    const int b = tid >> 3, i2 = tid & 7;
    xA[0][b*32 + i2] = f2bf(xg[(size_t)(gb0 + b)*(TLEN*8) + i2]);
  }
  __syncthreads();  // b1cL + x(0) ready; all init done

  f32x4 c0s = {0.f,0.f,0.f,0.f};   // holds 2*log2(e)*c  (scaled cell state)
  f32x4 c1s = {0.f,0.f,0.f,0.f};

  const int aoffX = ln*32   + q*8;            // x A-frag offset (shorts)
  const int aoffH = ln*HSTR + q*8;            // h A-frag offset, + kk*32
  const int hwoff = (q*4)*HSTR + (w<<4) + ln; // h write base: rows q*4+r, col j
  const int cbL   = (q << 12) + ((w << 4) + ln) * 8;  // WhhL frag base; + nt*1024 + kk*16384

  // ---- activation tail: prescaled z -> exp2 direct; FULLY merged reciprocals:
  //   c  = [cs*(1+ei)(1+eg) + (SC_G*eg-SC_G)*(1+ef)] / ((1+ef)(1+ei)(1+eg))
  //   h  = (ec-1) / ((1+eo)(1+ec))
  //   5 exp2 + 2 rcp per element ----
  auto gates = [&](const f32x4& gi, const f32x4& gf, const f32x4& gg, const f32x4& go,
                   f32x4& cs, short* hw) {
    float hv[4];
    #pragma unroll
    for (int r = 0; r < 4; r++) {
      float ei = __builtin_amdgcn_exp2f(gi[r]);     // = exp(-z_i)
      float ef = __builtin_amdgcn_exp2f(gf[r]);     // = exp(-z_f)
      float eg = __builtin_amdgcn_exp2f(gg[r]);     // = exp(+2 z_g)
      float eo = __builtin_amdgcn_exp2f(go[r]);     // = exp(-z_o)
      float pi  = 1.0f + ei, pf = 1.0f + ef, pg = 1.0f + eg;
      float pig = pi * pg;
      float num = cs[r] * pig + (SC_G * eg - SC_G) * pf;
      float c   = num * __builtin_amdgcn_rcpf(pf * pig);   // scaled cell state
      cs[r] = c;
      float ec  = __builtin_amdgcn_exp2f(c);        // = exp(2 c_true)
      float roc = __builtin_amdgcn_rcpf((1.0f + eo) * (1.0f + ec));
      hv[r] = (ec - 1.0f) * roc;                    // = o * tanh(c_true)
    }
    unsigned p01 = cvt_pk_bf16(hv[0], hv[1]);
    unsigned p23 = cvt_pk_bf16(hv[2], hv[3]);
    hw[0*HSTR] = (short)p01;
    hw[1*HSTR] = (short)(p01 >> 16);
    hw[2*HSTR] = (short)p23;
    hw[3*HSTR] = (short)(p23 >> 16);
  };

  // -------- layer 0 (serial form, used by decoder) --------
  auto layer0 = [&](const short* xr, const bf16x8* ah, short* h0w) {
    bf16x8 ax = *(const bf16x8*)(xr + aoffX);
    f32x4 ac[NT];
    #pragma unroll
    for (int nt = 0; nt < NT; nt++) {
      f32x4 a = {0.f,0.f,0.f,0.f};
      a = __builtin_amdgcn_mfma_f32_16x16x32_bf16(ax, wih0f[nt], a, 0, 0, 0);
      #pragma unroll
      for (int kk = 0; kk < 4; kk++) {
        bf16x8 wb = *(const bf16x8*)(WhhL + cbL + nt*1024 + kk*16384);
        a = __builtin_amdgcn_mfma_f32_16x16x32_bf16(ah[kk], wb, a, 0, 0, 0);
      }
      ac[nt] = a;
    }
    gates(ac[0], ac[1], ac[2], ac[3], c0s, h0w + hwoff);
  };

  // -------- layer 1 (serial form, used by decoder) --------
  auto layer1 = [&](const bf16x8* ah, const short* h1r, short* h1w) {
    bf16x8 a1k[4];
    #pragma unroll
    for (int kk = 0; kk < 4; kk++)
      a1k[kk] = *(const bf16x8*)(h1r + aoffH + kk*32);
    f32x4 ac[NT];
    #pragma unroll
    for (int nt = 0; nt < NT; nt++) {
      f32x4 a; a[0]=a[1]=a[2]=a[3]=b1sum[nt];
      #pragma unroll
      for (int kk = 0; kk < 4; kk++) {
        a = __builtin_amdgcn_mfma_f32_16x16x32_bf16(ah[kk],  wih1f[nt][kk], a, 0, 0, 0);
        a = __builtin_amdgcn_mfma_f32_16x16x32_bf16(a1k[kk], whh1f[nt][kk], a, 0, 0, 0);
      }
      ac[nt] = a;
    }
    gates(ac[0], ac[1], ac[2], ac[3], c1s, h1w + hwoff);
  };

  // ================= encoder: pipelined, ONE barrier per iteration ==========
  // iter k: layer0(k) [x(k), h0(k-1) -> h0(k)]  ||  layer1(k-1) [h0(k-1), h1(k-2) -> h1(k-1)]
  // ISSUE ORDER within the wave: all ds_reads -> ALL 52 MFMAs -> all gates VALU.
  // In-order issue + async pipes => gates VALU issues while MFMAs still execute.
  auto enc_iter = [&](int k, const short* xr, short* xw,
                      const short* h0r, short* h0w,
                      const short* h1r, short* h1w, bool doL0, bool doL1) {
    const int b = tid >> 3, i2 = tid & 7;
    const bool pf = doL0 && (k + 1 < TLEN) && (tid < 128);
    float xp = 0.f;
    if (pf) xp = xg[(size_t)(gb0 + b)*(TLEN*8) + (size_t)(k+1)*8 + i2]; // in flight under compute
    bf16x8 ah[4];                       // h0(k-1) frags, shared by both layers
    #pragma unroll
    for (int kk = 0; kk < 4; kk++)
      ah[kk] = *(const bf16x8*)(h0r + aoffH + kk*32);
    bf16x8 a1k[4];
    if (doL1) {
      #pragma unroll
      for (int kk = 0; kk < 4; kk++)
        a1k[kk] = *(const bf16x8*)(h1r + aoffH + kk*32);
    }
    f32x4 ac0[NT], ac1[NT];
    if (doL0) {                          // L0 MFMA block (20)
      bf16x8 ax = *(const bf16x8*)(xr + aoffX);
      #pragma unroll
      for (int nt = 0; nt < NT; nt++) {
        f32x4 a = {0.f,0.f,0.f,0.f};
        a = __builtin_amdgcn_mfma_f32_16x16x32_bf16(ax, wih0f[nt], a, 0, 0, 0);
        #pragma unroll
        for (int kk = 0; kk < 4; kk++) {
          bf16x8 wb = *(const bf16x8*)(WhhL + cbL + nt*1024 + kk*16384);
          a = __builtin_amdgcn_mfma_f32_16x16x32_bf16(ah[kk], wb, a, 0, 0, 0);
        }
        ac0[nt] = a;
      }
    }
    if (doL1) {                          // L1 MFMA block (32) — issued before any gates
      #pragma unroll
      for (int nt = 0; nt < NT; nt++) {
        f32x4 a; a[0]=a[1]=a[2]=a[3]=b1sum[nt];
        #pragma unroll
        for (int kk = 0; kk < 4; kk++) {
          a = __builtin_amdgcn_mfma_f32_16x16x32_bf16(ah[kk],  wih1f[nt][kk], a, 0, 0, 0);
          a = __builtin_amdgcn_mfma_f32_16x16x32_bf16(a1k[kk], whh1f[nt][kk], a, 0, 0, 0);
        }
        ac1[nt] = a;
      }
    }
    if (doL0) gates(ac0[0], ac0[1], ac0[2], ac0[3], c0s, h0w + hwoff);
    if (doL1) gates(ac1[0], ac1[1], ac1[2], ac1[3], c1s, h1w + hwoff);
    if (pf) xw[b*32 + i2] = f2bf(xp);   // other x buffer: no race with xr readers
    __syncthreads();                    // h0(k), h1(k-1), x(k+1) visible
  };

  enc_iter(0, xA[0], xA[1], h0A[1], h0A[0], h1A[0], h1A[1], true, false);
  enc_iter(1, xA[1], xA[0], h0A[0], h0A[1], h1A[1], h1A[0], true, true);
  for (int k = 2; k < TLEN; k += 2) {
    enc_iter(k,     xA[0], xA[1], h0A[1], h0A[0], h1A[0], h1A[1], true, true);
    enc_iter(k + 1, xA[1], xA[0], h0A[0], h0A[1], h1A[1], h1A[0], true, true);
  }
  enc_iter(TLEN, xA[0], xA[1], h0A[1], h0A[0], h1A[0], h1A[1], false, true);
  // state: h0(511) in h0A[1], h1(511) in h1A[1], x(511) in xA[1].

  // ---- decoder-only weights materialized AFTER the encoder (fewer live regs
  //      in the hot loop); sLs persists in LDS. FC path is NOT prescaled. ----
  bf16x8 w1f[4];
  #pragma unroll
  for (int kk = 0; kk < 4; kk++) {
    bf16x8 r;
    if (w < 4) {
      int p = w*16 + ln;
      #pragma unroll
      for (int j = 0; j < 8; j++) {
        int k = kk*32 + q*8 + j;
        r[j] = f2bf(sLs[k] * W1[p*HD + k]);
      }
    } else {
      #pragma unroll
      for (int j = 0; j < 8; j++) r[j] = 0;
    }
    w1f[kk] = r;
  }

  // ================= decoder (serial; rb flipped since state sits in [1]) ====
  for (int s = 0; s < ps; s++) {
    int rb = (s & 1) ^ 1;
    __syncthreads();  // xA[1] + buffer turnover ready
    {
      bf16x8 ah[4];
      #pragma unroll
      for (int kk = 0; kk < 4; kk++)
        ah[kk] = *(const bf16x8*)(h0A[rb] + aoffH + kk*32);
      layer0(xA[1], ah, h0A[rb^1]);
    }
    __syncthreads();
    {
      bf16x8 ah[4];
      #pragma unroll
      for (int kk = 0; kk < 4; kk++)
        ah[kk] = *(const bf16x8*)(h0A[rb^1] + aoffH + kk*32);
      layer1(ah, h1A[rb], h1A[rb^1]);
    }
    const short* h1n = h1A[rb^1];
    __syncthreads();  // h1 new visible to all waves
    // ---- a1 = relu(h1 @ (bn-folded W1)^T + b1c): MFMA on waves 0..3;
    //      stored b-major (stride 68) for vectorized FC reads
    if (w < 4) {
      f32x4 aa = {0.f,0.f,0.f,0.f};
      #pragma unroll
      for (int kk = 0; kk < 4; kk++) {
        bf16x8 ahn = *(const bf16x8*)(h1n + aoffH + kk*32);
        aa = __builtin_amdgcn_mfma_f32_16x16x32_bf16(ahn, w1f[kk], aa, 0, 0, 0);
      }
      float bb = b1cL[w*16 + ln];
      #pragma unroll
      for (int r = 0; r < 4; r++)
        a1L[(q*4 + r)*68 + (w*16 + ln)] = fmaxf(aa[r] + bb, 0.f);
    }
    __syncthreads();
    // ---- concurrent, vectorized (float4) FC:
    //      xin = a1 @ Wc^T + bc (tid<128) ; dout = a1 @ W2^T + b2 (tid 128..191)
    if (tid < 128) {
      int b = tid >> 3, i2 = tid & 7;
      const f32x4* ar = (const f32x4*)(a1L + b*68);
      const f32x4* wr = (const f32x4*)(WcL + i2*68);
      float v = bcL[i2];
      #pragma unroll
      for (int p4 = 0; p4 < 16; p4++) {
        f32x4 av = ar[p4], wv = wr[p4];
        v += av[0]*wv[0] + av[1]*wv[1] + av[2]*wv[2] + av[3]*wv[3];
      }
      xA[1][b*32 + i2] = f2bf(v);
    } else if (tid < 192) {
      int t = tid - 128, b = t & 15, o = t >> 4;
      const f32x4* ar = (const f32x4*)(a1L + b*68);
      const f32x4* wr = (const f32x4*)(W2L + o*68);
      float acc2 = b2L[o];
      #pragma unroll
      for (int p4 = 0; p4 < 16; p4++) {
        f32x4 av = ar[p4], wv = wr[p4];
        acc2 += av[0]*wv[0] + av[1]*wv[1] + av[2]*wv[2] + av[3]*wv[3];
      }
      dout[(size_t)(gb0 + b)*(ps*4) + s*4 + o] = acc2;
    }
  }
}

extern "C" void kernel_launch(void* const* d_in, const int* in_sizes, int n_in,
                              void* d_out, int out_size, void* d_ws, size_t ws_size,
                              hipStream_t stream) {
  (void)in_sizes; (void)n_in; (void)d_ws; (void)ws_size; (void)out_size;
  lstm_kernel<<<dim3(4096/BT), dim3(THREADS), 0, stream>>>(
      (const float*)d_in[0],  (const float*)d_in[1],  (const float*)d_in[2],
      (const float*)d_in[3],  (const float*)d_in[4],  (const float*)d_in[5],
      (const float*)d_in[6],  (const float*)d_in[7],  (const float*)d_in[8],
      (const float*)d_in[9],  (const float*)d_in[10], (const float*)d_in[11],
      (const float*)d_in[12], (const float*)d_in[13], (const float*)d_in[14],
      (const float*)d_in[15], (const float*)d_in[16], (const float*)d_in[17],
      (const float*)d_in[18], (const int*)d_in[19],   (float*)d_out);
}